// Round 1
// baseline (313.626 us; speedup 1.0000x reference)
//
#include <hip/hip_runtime.h>
#include <math.h>

// Problem constants (reference: N=4194304, D=8, H=16, E=2)
#define BLOCKS  2048
#define THREADS 256

// Main kernel: grid-stride over tokens, one token per lane per iteration.
// Weights staged in LDS. Per-block partial sum -> blocksums[blockIdx.x].
__global__ void __launch_bounds__(THREADS)
moe_main(const float* __restrict__ inp,
         const float* __restrict__ Wa,  const float* __restrict__ ba,
         const float* __restrict__ Wb,  const float* __restrict__ bb,
         const float* __restrict__ Wg,  const float* __restrict__ bg,
         const float* __restrict__ We1, const float* __restrict__ be1,
         const float* __restrict__ We2, const float* __restrict__ be2,
         float* __restrict__ blocksums, int ntok)
{
    __shared__ float sWa[128];   // [d][j] d<8, j<16
    __shared__ float sba[16];
    __shared__ float sWb[128];   // [j][d] j<16, d<8
    __shared__ float sbb[8];
    __shared__ float swgd[8];    // Wg[:,1]-Wg[:,0]
    __shared__ float sbgd;
    __shared__ float sWe1[256];  // [e][d][j]
    __shared__ float sbe1[32];   // [e][j]
    __shared__ float ss2[32];    // [e][j] = sum_d We2[e][j][d]
    __shared__ float ssb2[2];    // sum_d be2[e][d]
    __shared__ float wavered[4];

    const int t = threadIdx.x;
    if (t < 128) {
        sWa[t]       = Wa[t];
        sWb[t]       = Wb[t];
        sWe1[t]      = We1[t];
        sWe1[128+t]  = We1[128+t];
    }
    if (t < 16) sba[t] = ba[t];
    if (t < 32) sbe1[t] = be1[t];
    if (t < 8)  { sbb[t] = bb[t]; swgd[t] = Wg[t*2+1] - Wg[t*2+0]; }
    if (t == 0) sbgd = bg[1] - bg[0];
    if (t < 32) {  // t = e*16 + h ; We2 flat idx = (e*16+h)*8 + d
        float s = 0.f;
        #pragma unroll
        for (int d = 0; d < 8; ++d) s += We2[t*8 + d];
        ss2[t] = s;
    }
    if (t < 2) {
        float s = 0.f;
        #pragma unroll
        for (int d = 0; d < 8; ++d) s += be2[t*8 + d];
        ssb2[t] = s;
    }
    __syncthreads();

    const int gtid   = blockIdx.x * THREADS + t;
    const int stride = BLOCKS * THREADS;

    float local_sum = 0.f;

    for (int i = gtid; i < ntok; i += stride) {
        const float4* p = (const float4*)(inp + (size_t)i * 8);
        float4 a0 = p[0];
        float4 a1 = p[1];
        float in[8] = {a0.x, a0.y, a0.z, a0.w, a1.x, a1.y, a1.z, a1.w};

        // layer A: u = relu(in @ Wa + ba)   [16]
        float rh[16];
        #pragma unroll
        for (int j = 0; j < 16; ++j) {
            float u = sba[j];
            #pragma unroll
            for (int d = 0; d < 8; ++d) u = fmaf(in[d], sWa[d*16 + j], u);
            rh[j] = fmaxf(u, 0.f);
        }

        // layer B: x = rh @ Wb + bb   [8]
        float x[8];
        #pragma unroll
        for (int d = 0; d < 8; ++d) {
            float v = sbb[d];
            #pragma unroll
            for (int j = 0; j < 16; ++j) v = fmaf(rh[j], sWb[j*8 + d], v);
            x[d] = v;
        }

        // gate: e = (x . wgd + bgd) > 0  (argmax over 2 logits, first-max ties -> e=0)
        float gd = sbgd;
        #pragma unroll
        for (int d = 0; d < 8; ++d) gd = fmaf(x[d], swgd[d], gd);
        const int e = gd > 0.f ? 1 : 0;

        // expert layer 1 + gelu + collapsed layer 2 (sum over d)
        const float* w1  = &sWe1[e * 128];
        const float* b1  = &sbe1[e * 16];
        const float* s2e = &ss2[e * 16];
        float acc = ssb2[e];
        #pragma unroll
        for (int h = 0; h < 16; ++h) {
            float tv = b1[h];
            #pragma unroll
            for (int d = 0; d < 8; ++d) tv = fmaf(x[d], w1[d*16 + h], tv);
            const float g = 0.5f * tv * (1.0f + erff(tv * 0.70710678118654752f));
            acc = fmaf(g, s2e[h], acc);
        }
        local_sum += acc;
    }

    // wave (64) reduction
    #pragma unroll
    for (int off = 32; off > 0; off >>= 1)
        local_sum += __shfl_down(local_sum, off);
    const int wave = t >> 6;
    const int lane = t & 63;
    if (lane == 0) wavered[wave] = local_sum;
    __syncthreads();
    if (t == 0)
        blocksums[blockIdx.x] = wavered[0] + wavered[1] + wavered[2] + wavered[3];
}

// Deterministic final reduction of BLOCKS partial sums.
__global__ void __launch_bounds__(256)
moe_reduce(const float* __restrict__ blocksums, float* __restrict__ out)
{
    __shared__ float wavered[4];
    float v = 0.f;
    for (int i = threadIdx.x; i < BLOCKS; i += 256) v += blocksums[i];
    #pragma unroll
    for (int off = 32; off > 0; off >>= 1)
        v += __shfl_down(v, off);
    const int wave = threadIdx.x >> 6;
    const int lane = threadIdx.x & 63;
    if (lane == 0) wavered[wave] = v;
    __syncthreads();
    if (threadIdx.x == 0)
        out[0] = wavered[0] + wavered[1] + wavered[2] + wavered[3];
}

extern "C" void kernel_launch(void* const* d_in, const int* in_sizes, int n_in,
                              void* d_out, int out_size, void* d_ws, size_t ws_size,
                              hipStream_t stream)
{
    const float* inp = (const float*)d_in[0];
    const float* Wa  = (const float*)d_in[1];
    const float* ba  = (const float*)d_in[2];
    const float* Wb  = (const float*)d_in[3];
    const float* bb  = (const float*)d_in[4];
    const float* Wg  = (const float*)d_in[5];
    const float* bg  = (const float*)d_in[6];
    const float* We1 = (const float*)d_in[7];
    const float* be1 = (const float*)d_in[8];
    const float* We2 = (const float*)d_in[9];
    const float* be2 = (const float*)d_in[10];

    const int ntok = in_sizes[0] / 8;
    float* blocksums = (float*)d_ws;
    float* out = (float*)d_out;

    hipLaunchKernelGGL(moe_main, dim3(BLOCKS), dim3(THREADS), 0, stream,
                       inp, Wa, ba, Wb, bb, Wg, bg, We1, be1, We2, be2,
                       blocksums, ntok);
    hipLaunchKernelGGL(moe_reduce, dim3(1), dim3(256), 0, stream,
                       blocksums, out);
}

// Round 2
// 264.116 us; speedup vs baseline: 1.1875x; 1.1875x over previous
//
#include <hip/hip_runtime.h>
#include <math.h>

// N=4194304 tokens, D=8, H=16, E=2
#define BLOCKS  2048
#define THREADS 256

// ---------------------------------------------------------------------------
// Prep kernel (1 tiny block): fold gate and second expert layer into ws.
//   wsc[0..7]   = Wg[:,1]-Wg[:,0]
//   wsc[8]      = bg[1]-bg[0]
//   wsc[9]      = sum_d be2[0][d]
//   wsc[10]     = sum_d be2[1][d]
//   wsc[16+e*16+h] = sum_d We2[e][h][d]
// ---------------------------------------------------------------------------
__global__ void moe_prep(const float* __restrict__ Wg, const float* __restrict__ bg,
                         const float* __restrict__ We2, const float* __restrict__ be2,
                         float* __restrict__ wsc)
{
    const int t = threadIdx.x;
    if (t < 8) wsc[t] = Wg[t * 2 + 1] - Wg[t * 2 + 0];
    if (t == 8) wsc[8] = bg[1] - bg[0];
    if (t == 9) {
        float s = 0.f;
        #pragma unroll
        for (int d = 0; d < 8; ++d) s += be2[d];
        wsc[9] = s;
    }
    if (t == 10) {
        float s = 0.f;
        #pragma unroll
        for (int d = 0; d < 8; ++d) s += be2[8 + d];
        wsc[10] = s;
    }
    if (t >= 16 && t < 48) {           // t-16 = e*16+h, We2 flat (e*16+h)*8+d
        const int idx = t - 16;
        float s = 0.f;
        #pragma unroll
        for (int d = 0; d < 8; ++d) s += We2[idx * 8 + d];
        wsc[t] = s;
    }
}

// Branch-free erf-based gelu, Abramowitz-Stegun 7.1.26 (|eps| <= ~2e-7).
__device__ __forceinline__ float gelu_erf(float v)
{
    const float z  = v * 0.70710678118654752f;
    const float az = fabsf(z);
    const float t  = __builtin_amdgcn_rcpf(fmaf(0.3275911f, az, 1.0f));
    float p = fmaf(1.061405429f, t, -1.453152027f);
    p = fmaf(p, t, 1.421413741f);
    p = fmaf(p, t, -0.284496736f);
    p = fmaf(p, t, 0.254829592f);
    p = p * t;
    const float ex   = __expf(-az * az);
    const float erfa = fmaf(-p, ex, 1.0f);     // erf(|z|) = 1 - p*exp(-z^2)
    const float erfz = copysignf(erfa, z);
    return 0.5f * v * (1.0f + erfz);
}

// ---------------------------------------------------------------------------
// Main kernel: all weights read via wave-uniform global loads (s_load / K$),
// no LDS in the hot loop. Both experts computed dense (SGPR-operand FMAs),
// one cndmask select. Per-block partial sum -> blocksums[blockIdx.x].
// ---------------------------------------------------------------------------
__global__ void __launch_bounds__(THREADS, 4)
moe_main(const float* __restrict__ inp,
         const float* __restrict__ Wa,  const float* __restrict__ ba,
         const float* __restrict__ Wb,  const float* __restrict__ bb,
         const float* __restrict__ We1, const float* __restrict__ be1,
         const float* __restrict__ wsc,
         float* __restrict__ blocksums, int ntok)
{
    __shared__ float wavered[4];

    const int t      = threadIdx.x;
    const int gtid   = blockIdx.x * THREADS + t;
    const int stride = BLOCKS * THREADS;

    float local_sum = 0.f;

    for (int i = gtid; i < ntok; i += stride) {
        const float4* p = (const float4*)(inp + (size_t)i * 8);
        const float4 a0 = p[0];
        const float4 a1 = p[1];
        const float in[8] = {a0.x, a0.y, a0.z, a0.w, a1.x, a1.y, a1.z, a1.w};

        // layer A: rh = relu(in @ Wa + ba)   [16]
        float rh[16];
        #pragma unroll
        for (int j = 0; j < 16; ++j) {
            float u = ba[j];
            #pragma unroll
            for (int d = 0; d < 8; ++d) u = fmaf(in[d], Wa[d * 16 + j], u);
            rh[j] = fmaxf(u, 0.f);
        }

        // layer B: x = rh @ Wb + bb   [8]
        float x[8];
        #pragma unroll
        for (int d = 0; d < 8; ++d) x[d] = bb[d];
        #pragma unroll
        for (int j = 0; j < 16; ++j) {
            #pragma unroll
            for (int d = 0; d < 8; ++d) x[d] = fmaf(rh[j], Wb[j * 8 + d], x[d]);
        }

        // gate: e = 1 iff l1 > l0 strictly (argmax first-max tie -> 0)
        float gd = wsc[8];
        #pragma unroll
        for (int d = 0; d < 8; ++d) gd = fmaf(x[d], wsc[d], gd);
        const bool sel = gd > 0.f;

        // expert layer 1, both experts dense (uniform weights -> SGPR fma)
        float t0[16], t1[16];
        #pragma unroll
        for (int h = 0; h < 16; ++h) { t0[h] = be1[h]; t1[h] = be1[16 + h]; }
        #pragma unroll
        for (int d = 0; d < 8; ++d) {
            #pragma unroll
            for (int h = 0; h < 16; ++h) {
                t0[h] = fmaf(x[d], We1[d * 16 + h],       t0[h]);
                t1[h] = fmaf(x[d], We1[128 + d * 16 + h], t1[h]);
            }
        }

        // select + gelu + collapsed expert layer 2 (sum over d folded in wsc)
        float acc0 = wsc[9];
        float acc1 = wsc[10];
        #pragma unroll
        for (int h = 0; h < 16; ++h) {
            const float tv = sel ? t1[h] : t0[h];
            const float g  = gelu_erf(tv);
            acc0 = fmaf(g, wsc[16 + h], acc0);
            acc1 = fmaf(g, wsc[32 + h], acc1);
        }
        local_sum += sel ? acc1 : acc0;
    }

    // wave (64) reduction, then 4 waves -> 1
    #pragma unroll
    for (int off = 32; off > 0; off >>= 1)
        local_sum += __shfl_down(local_sum, off);
    const int wave = t >> 6;
    const int lane = t & 63;
    if (lane == 0) wavered[wave] = local_sum;
    __syncthreads();
    if (t == 0)
        blocksums[blockIdx.x] = wavered[0] + wavered[1] + wavered[2] + wavered[3];
}

// Deterministic final reduction of BLOCKS partial sums.
__global__ void __launch_bounds__(256)
moe_reduce(const float* __restrict__ blocksums, float* __restrict__ out)
{
    __shared__ float wavered[4];
    float v = 0.f;
    for (int i = threadIdx.x; i < BLOCKS; i += 256) v += blocksums[i];
    #pragma unroll
    for (int off = 32; off > 0; off >>= 1)
        v += __shfl_down(v, off);
    const int wave = threadIdx.x >> 6;
    const int lane = threadIdx.x & 63;
    if (lane == 0) wavered[wave] = v;
    __syncthreads();
    if (threadIdx.x == 0)
        out[0] = wavered[0] + wavered[1] + wavered[2] + wavered[3];
}

extern "C" void kernel_launch(void* const* d_in, const int* in_sizes, int n_in,
                              void* d_out, int out_size, void* d_ws, size_t ws_size,
                              hipStream_t stream)
{
    const float* inp = (const float*)d_in[0];
    const float* Wa  = (const float*)d_in[1];
    const float* ba  = (const float*)d_in[2];
    const float* Wb  = (const float*)d_in[3];
    const float* bb  = (const float*)d_in[4];
    const float* Wg  = (const float*)d_in[5];
    const float* bg  = (const float*)d_in[6];
    const float* We1 = (const float*)d_in[7];
    const float* be1 = (const float*)d_in[8];
    const float* We2 = (const float*)d_in[9];
    const float* be2 = (const float*)d_in[10];

    const int ntok = in_sizes[0] / 8;

    float* wsc       = (float*)d_ws;              // 64 floats of folded weights
    float* blocksums = (float*)d_ws + 64;         // BLOCKS floats
    float* out       = (float*)d_out;

    hipLaunchKernelGGL(moe_prep, dim3(1), dim3(64), 0, stream,
                       Wg, bg, We2, be2, wsc);
    hipLaunchKernelGGL(moe_main, dim3(BLOCKS), dim3(THREADS), 0, stream,
                       inp, Wa, ba, Wb, bb, We1, be1, wsc, blocksums, ntok);
    hipLaunchKernelGGL(moe_reduce, dim3(1), dim3(256), 0, stream,
                       blocksums, out);
}

// Round 3
// 73.568 us; speedup vs baseline: 4.2631x; 3.5901x over previous
//
#include <hip/hip_runtime.h>
#include <math.h>

// N=4194304 tokens, D=8, H=16, E=2
#define BLOCKS  2048
#define THREADS 256
#define NWAVES  (BLOCKS * THREADS / 64)   // 8192 waves

typedef __attribute__((ext_vector_type(8))) short bf16x8;  // 8 bf16 (4 VGPRs)
typedef __attribute__((ext_vector_type(4))) float f32x4;

union BF8 { unsigned u[4]; bf16x8 v; };

// f32 -> bf16 round-to-nearest (ties-up; bias negligible), packed pair.
__device__ __forceinline__ unsigned pack_bf16(float lo, float hi)
{
    const unsigned a = __float_as_uint(lo) + 0x8000u;
    const unsigned b = __float_as_uint(hi) + 0x8000u;
    return (a >> 16) | (b & 0xffff0000u);
}

// Branch-free erf-based gelu, Abramowitz-Stegun 7.1.26 (|eps| ~ 2e-7).
__device__ __forceinline__ float gelu_erf(float v)
{
    const float z  = v * 0.70710678118654752f;
    const float az = fabsf(z);
    const float t  = __builtin_amdgcn_rcpf(fmaf(0.3275911f, az, 1.0f));
    float p = fmaf(1.061405429f, t, -1.453152027f);
    p = fmaf(p, t, 1.421413741f);
    p = fmaf(p, t, -0.284496736f);
    p = fmaf(p, t, 0.254829592f);
    p = p * t;
    const float ex   = __expf(-az * az);
    const float erfa = fmaf(-p, ex, 1.0f);
    const float erfz = copysignf(erfa, z);
    return 0.5f * v * (1.0f + erfz);
}

// ---------------------------------------------------------------------------
// Prep: fold Wb/bb into gate + expert layers; collapse expert layer 2 (output
// is summed over d, so We2 reduces to per-h dot vectors).
//   wsc[0:16)    wg16[f]   = sum_d Wb[f][d] * (Wg[d][1]-Wg[d][0])
//   wsc[16]      cg        = sum_d bb[d] * wgd[d] + (bg1 - bg0)
//   wsc[17]      sb2_0     = sum_d be2[0][d]     ; wsc[18] sb2_1
//   wsc[32:64)   cb_e[h]   = sum_d bb[d]*We1[e][d][h] + be1[e][h]   (e-major)
//   wsc[64:96)   s2_e[h]   = sum_d We2[e][h][d]                     (e-major)
//   wsc[128:640) M_e[f][h] = sum_d Wb[f][d]*We1[e][d][h]  (M0 @128, M1 @384)
// ---------------------------------------------------------------------------
__global__ void moe_prep(const float* __restrict__ Wb,  const float* __restrict__ bb,
                         const float* __restrict__ Wg,  const float* __restrict__ bg,
                         const float* __restrict__ We1, const float* __restrict__ be1,
                         const float* __restrict__ We2, const float* __restrict__ be2,
                         float* __restrict__ wsc)
{
    const int t = threadIdx.x;
    if (t < 16) {
        float s = 0.f;
        #pragma unroll
        for (int d = 0; d < 8; ++d)
            s += Wb[t * 8 + d] * (Wg[d * 2 + 1] - Wg[d * 2 + 0]);
        wsc[t] = s;
    }
    if (t == 16) {
        float s = bg[1] - bg[0];
        #pragma unroll
        for (int d = 0; d < 8; ++d) s += bb[d] * (Wg[d * 2 + 1] - Wg[d * 2 + 0]);
        wsc[16] = s;
    }
    if (t == 17 || t == 18) {
        const int e = t - 17;
        float s = 0.f;
        #pragma unroll
        for (int d = 0; d < 8; ++d) s += be2[e * 8 + d];
        wsc[t] = s;
    }
    if (t >= 32 && t < 64) {   // cb_e[h]
        const int e = (t - 32) >> 4, h = t & 15;
        float s = be1[e * 16 + h];
        #pragma unroll
        for (int d = 0; d < 8; ++d) s += bb[d] * We1[e * 128 + d * 16 + h];
        wsc[t] = s;
    }
    if (t >= 64 && t < 96) {   // s2_e[h]
        const int e = (t - 64) >> 4, h = t & 15;
        float s = 0.f;
        #pragma unroll
        for (int d = 0; d < 8; ++d) s += We2[(e * 16 + h) * 8 + d];
        wsc[t] = s;
    }
    if (t >= 128 && t < 640) { // M_e[f][h]
        const int idx = t - 128;
        const int e = idx >> 8, f = (idx >> 4) & 15, h = idx & 15;
        float s = 0.f;
        #pragma unroll
        for (int d = 0; d < 8; ++d) s += Wb[f * 8 + d] * We1[e * 128 + d * 16 + h];
        wsc[128 + idx] = s;
    }
}

// ---------------------------------------------------------------------------
// Main: 64 tokens per wave-iteration.
//  - layer A on MFMA: A = Wa^T padded [16h x K32(8)], B = tokens [K32(8) x 16],
//    bias in C accumulator; relu on C regs.
//  - gate from rh C-layout (col=lane&15=token) via 4 fma + xor16/xor32 butterfly.
//  - expert layer on MFMA: A = M_e [16h x K32(16f)], B = rh refragmented via
//    pack+ds_bpermute; bias in C. Both experts dense, cndmask select.
//  - gelu + collapsed second layer dot, per-lane accumulate.
// ---------------------------------------------------------------------------
__global__ void __launch_bounds__(THREADS, 4)
moe_main(const float* __restrict__ inp,
         const float* __restrict__ Wa, const float* __restrict__ ba,
         const float* __restrict__ wsc,
         float* __restrict__ blocksums, int ntok)
{
    __shared__ float wavered[4];
    const int t  = threadIdx.x;
    const int l  = t & 63;
    const int lg = l >> 4;
    const int lr = l & 15;
    const bool lo16 = (l < 16);
    const bool lo32 = (l < 32);

    // ---- fragment preloads (once) ----
    BF8 aWa, aM0, aM1;
    #pragma unroll
    for (int j2 = 0; j2 < 4; ++j2) {
        // layer A weights: A[h=lr][k=d=2*j2(+1)] = Wa[d*16+h]; zero for k>=8
        const float w0 = lo16 ? Wa[(2 * j2) * 16 + lr]     : 0.f;
        const float w1 = lo16 ? Wa[(2 * j2 + 1) * 16 + lr] : 0.f;
        aWa.u[j2] = pack_bf16(w0, w1);
        // expert weights: A[h=lr][k=f=8*lg+2*j2(+1)] = M_e[f][h]; zero k>=16
        const int f0 = 8 * lg + 2 * j2;
        const float m00 = lo32 ? wsc[128 + f0 * 16 + lr]       : 0.f;
        const float m01 = lo32 ? wsc[128 + (f0 + 1) * 16 + lr] : 0.f;
        aM0.u[j2] = pack_bf16(m00, m01);
        const float m10 = lo32 ? wsc[384 + f0 * 16 + lr]       : 0.f;
        const float m11 = lo32 ? wsc[384 + (f0 + 1) * 16 + lr] : 0.f;
        aM1.u[j2] = pack_bf16(m10, m11);
    }

    f32x4 cba, ccb0, ccb1, vwg, vs20, vs21;
    #pragma unroll
    for (int r = 0; r < 4; ++r) {
        const int h = lg * 4 + r;           // C row for this lane/reg
        cba[r]  = ba[h];
        vwg[r]  = wsc[h];
        ccb0[r] = wsc[32 + h];
        ccb1[r] = wsc[48 + h];
        vs20[r] = wsc[64 + h];
        vs21[r] = wsc[80 + h];
    }
    const float cg4  = wsc[16] * 0.25f;     // x4 lane-groups in butterfly
    const float sbq0 = wsc[17] * 0.25f;     // bias added by 4 lanes per token
    const float sbq1 = wsc[18] * 0.25f;

    int addrB[4];                           // rh -> B-frag bpermute addresses
    #pragma unroll
    for (int j = 0; j < 4; ++j)
        addrB[j] = ((lg * 2 + (j >> 1)) * 16 + lr) * 4;

    const int gwave = (blockIdx.x * THREADS + t) >> 6;
    float local = 0.f;

    for (long long base = (long long)gwave * 64; base + 64 <= ntok;
         base += (long long)NWAVES * 64) {
        const float4* p = (const float4*)(inp + (base + l) * 8);
        const float4 a0 = p[0];
        const float4 a1 = p[1];
        unsigned pin[4];
        pin[0] = pack_bf16(a0.x, a0.y);
        pin[1] = pack_bf16(a0.z, a0.w);
        pin[2] = pack_bf16(a1.x, a1.y);
        pin[3] = pack_bf16(a1.z, a1.w);

        #pragma unroll
        for (int m = 0; m < 4; ++m) {
            // B-frag: tokens m*16..m*16+15; lane l<16 holds token m*16+lr, k=d
            const int srcA = m * 64 + lr * 4;
            BF8 bin;
            #pragma unroll
            for (int j = 0; j < 4; ++j) {
                const int v = __builtin_amdgcn_ds_bpermute(srcA, (int)pin[j]);
                bin.u[j] = lo16 ? (unsigned)v : 0u;
            }
            const f32x4 C = __builtin_amdgcn_mfma_f32_16x16x32_bf16(
                                aWa.v, bin.v, cba, 0, 0, 0);
            f32x4 rh;
            #pragma unroll
            for (int r = 0; r < 4; ++r) rh[r] = fmaxf(C[r], 0.f);

            // gate: gd[token=lr] = cg + sum_f rh[f]*wg16[f]
            float pg = cg4;
            #pragma unroll
            for (int r = 0; r < 4; ++r) pg = fmaf(rh[r], vwg[r], pg);
            pg += __shfl_xor(pg, 16);
            pg += __shfl_xor(pg, 32);
            const bool sel = pg > 0.f;       // argmax tie -> expert 0

            // rh -> B-frag [K=16 features x N=16 tokens]
            const unsigned pr0 = pack_bf16(rh[0], rh[1]);
            const unsigned pr1 = pack_bf16(rh[2], rh[3]);
            BF8 bb2;
            #pragma unroll
            for (int j = 0; j < 4; ++j) {
                const int v = __builtin_amdgcn_ds_bpermute(
                                  addrB[j], (int)((j & 1) ? pr1 : pr0));
                bb2.u[j] = lo32 ? (unsigned)v : 0u;
            }
            const f32x4 C0 = __builtin_amdgcn_mfma_f32_16x16x32_bf16(
                                 aM0.v, bb2.v, ccb0, 0, 0, 0);
            const f32x4 C1 = __builtin_amdgcn_mfma_f32_16x16x32_bf16(
                                 aM1.v, bb2.v, ccb1, 0, 0, 0);

            #pragma unroll
            for (int r = 0; r < 4; ++r) {
                const float pre = sel ? C1[r] : C0[r];
                const float g   = gelu_erf(pre);
                const float s2  = sel ? vs21[r] : vs20[r];
                local = fmaf(g, s2, local);
            }
            local += sel ? sbq1 : sbq0;
        }
    }

    // wave reduce + block reduce
    #pragma unroll
    for (int off = 32; off > 0; off >>= 1)
        local += __shfl_down(local, off);
    const int wave = t >> 6;
    if ((t & 63) == 0) wavered[wave] = local;
    __syncthreads();
    if (t == 0)
        blocksums[blockIdx.x] = wavered[0] + wavered[1] + wavered[2] + wavered[3];
}

__global__ void __launch_bounds__(256)
moe_reduce(const float* __restrict__ blocksums, float* __restrict__ out)
{
    __shared__ float wavered[4];
    float v = 0.f;
    for (int i = threadIdx.x; i < BLOCKS; i += 256) v += blocksums[i];
    #pragma unroll
    for (int off = 32; off > 0; off >>= 1)
        v += __shfl_down(v, off);
    if ((threadIdx.x & 63) == 0) wavered[threadIdx.x >> 6] = v;
    __syncthreads();
    if (threadIdx.x == 0)
        out[0] = wavered[0] + wavered[1] + wavered[2] + wavered[3];
}

extern "C" void kernel_launch(void* const* d_in, const int* in_sizes, int n_in,
                              void* d_out, int out_size, void* d_ws, size_t ws_size,
                              hipStream_t stream)
{
    const float* inp = (const float*)d_in[0];
    const float* Wa  = (const float*)d_in[1];
    const float* ba  = (const float*)d_in[2];
    const float* Wb  = (const float*)d_in[3];
    const float* bb  = (const float*)d_in[4];
    const float* Wg  = (const float*)d_in[5];
    const float* bg  = (const float*)d_in[6];
    const float* We1 = (const float*)d_in[7];
    const float* be1 = (const float*)d_in[8];
    const float* We2 = (const float*)d_in[9];
    const float* be2 = (const float*)d_in[10];

    const int ntok = in_sizes[0] / 8;

    float* wsc       = (float*)d_ws;        // 640 floats of folded weights
    float* blocksums = (float*)d_ws + 640;  // BLOCKS floats
    float* out       = (float*)d_out;

    hipLaunchKernelGGL(moe_prep, dim3(1), dim3(640), 0, stream,
                       Wb, bb, Wg, bg, We1, be1, We2, be2, wsc);
    hipLaunchKernelGGL(moe_main, dim3(BLOCKS), dim3(THREADS), 0, stream,
                       inp, Wa, ba, wsc, blocksums, ntok);
    hipLaunchKernelGGL(moe_reduce, dim3(1), dim3(256), 0, stream,
                       blocksums, out);
}